// Round 1
// baseline (127.640 us; speedup 1.0000x reference)
//
#include <hip/hip_runtime.h>

// B = 4194304 samples. x: [B,2] f32, parameters: [B,4] f32, out: [B,2] f32.
// Each thread handles 2 samples -> all global accesses are float4 (16B/lane).

__device__ __forceinline__ float2 qsample(float x0, float x1, float4 p) {
    float sa, ca, sb, cb, s2, c2, s3, c3;
    __sincosf((x0 + p.x) * 0.5f, &sa, &ca);
    __sincosf((x1 + p.y) * 0.5f, &sb, &cb);
    __sincosf(p.z * 0.5f, &s2, &c2);
    __sincosf(p.w * 0.5f, &s3, &c3);

    // state after RY(a) on q0, RY(b) on q1, then CX(ctrl=q0, tgt=q1):
    // s[j1][j0]
    float s00 = cb * ca;
    float s01 = sb * sa;
    float s10 = sb * ca;
    float s11 = cb * sa;

    // RY(p2) on q0: mix within each row (last axis)
    float t00 = c2 * s00 - s2 * s01;
    float t01 = s2 * s00 + c2 * s01;
    float t10 = c2 * s10 - s2 * s11;
    float t11 = s2 * s10 + c2 * s11;

    // RY(p3) on q1: mix within each column (middle axis)
    float u00 = c3 * t00 - s3 * t10;
    float u01 = c3 * t01 - s3 * t11;
    float u10 = s3 * t00 + c3 * t10;
    float u11 = s3 * t01 + c3 * t11;

    float p00 = u00 * u00, p01 = u01 * u01, p10 = u10 * u10, p11 = u11 * u11;
    float z0 = (p00 + p10) - (p01 + p11);  // <Z> on q0 (last axis)
    float z1 = (p00 + p01) - (p10 + p11);  // <Z> on q1 (middle axis)
    return make_float2(z0, z1);
}

__global__ void __launch_bounds__(256)
quantum_layer_kernel(const float4* __restrict__ x2,   // [B/2] : 2 samples' x per elem
                     const float4* __restrict__ p4,   // [B]   : 1 sample's params per elem
                     float4* __restrict__ out2,       // [B/2] : 2 samples' (z0,z1) per elem
                     int npairs) {
    int i = blockIdx.x * blockDim.x + threadIdx.x;
    if (i >= npairs) return;

    float4 xv = x2[i];           // x0_a, x1_a, x0_b, x1_b
    float4 pa = p4[2 * i + 0];   // sample a params
    float4 pb = p4[2 * i + 1];   // sample b params

    float2 za = qsample(xv.x, xv.y, pa);
    float2 zb = qsample(xv.z, xv.w, pb);

    out2[i] = make_float4(za.x, za.y, zb.x, zb.y);
}

extern "C" void kernel_launch(void* const* d_in, const int* in_sizes, int n_in,
                              void* d_out, int out_size, void* d_ws, size_t ws_size,
                              hipStream_t stream) {
    const float4* x2 = (const float4*)d_in[0];   // [B,2] f32 -> B/2 float4
    const float4* p4 = (const float4*)d_in[1];   // [B,4] f32 -> B float4
    float4* out2 = (float4*)d_out;               // [B,2] f32 -> B/2 float4

    int B = in_sizes[0] / 2;     // number of samples
    int npairs = B / 2;          // 2 samples per thread
    int block = 256;
    int grid = (npairs + block - 1) / block;
    quantum_layer_kernel<<<grid, block, 0, stream>>>(x2, p4, out2, npairs);
}